// Round 17
// baseline (204.584 us; speedup 1.0000x reference)
//
#include <hip/hip_runtime.h>

typedef __bf16 bf16x8 __attribute__((ext_vector_type(8)));
typedef __bf16 bf16x4 __attribute__((ext_vector_type(4)));
typedef float f32x4 __attribute__((ext_vector_type(4)));
typedef float f32x16 __attribute__((ext_vector_type(16)));
typedef unsigned int u32;

#define T_LEN 4096

__device__ __forceinline__ f32x4 mfma16(bf16x8 a, bf16x8 b, f32x4 c) {
    return __builtin_amdgcn_mfma_f32_16x16x32_bf16(a, b, c, 0, 0, 0);
}
__device__ __forceinline__ f32x16 mfma32(bf16x8 a, bf16x8 b, f32x16 c) {
    return __builtin_amdgcn_mfma_f32_32x32x16_bf16(a, b, c, 0, 0, 0);
}
__device__ __forceinline__ u32 packbf(float lo, float hi) {
    union { __bf16 e[2]; u32 w; } u;
    u.e[0] = (__bf16)lo; u.e[1] = (__bf16)hi;
    return u.w;
}
__device__ __forceinline__ f32x16 zero16() {
    f32x16 z;
    #pragma unroll
    for (int i = 0; i < 16; i++) z[i] = 0.f;
    return z;
}

// ---- W fp32 -> bf16 (row-major) + zero the global-barrier counter ----
__global__ __launch_bounds__(256) void convert_w_kernel(
    const float* __restrict__ Wq, const float* __restrict__ Wk,
    const float* __restrict__ Wv, __bf16* __restrict__ wb, u32* bar)
{
    if (blockIdx.x == 0 && threadIdx.x == 0)
        __hip_atomic_store(bar, 0u, __ATOMIC_RELAXED, __HIP_MEMORY_SCOPE_AGENT);
    int i = blockIdx.x * 256 + threadIdx.x;      // 49152 threads, 4 elems each
    int m = i >> 14, off = (i & 16383) << 2;
    const float* s = (m == 0 ? Wq : (m == 1 ? Wk : Wv)) + off;
    float4 f = *(const float4*)s;
    bf16x4 h = { (__bf16)f.x, (__bf16)f.y, (__bf16)f.z, (__bf16)f.w };
    *(bf16x4*)(wb + (m << 16) + off) = h;
}

// ---------------- FUSED proj + global barrier + flash ----------------
// 256 blocks x 1024 threads = exactly 1 block/CU (co-residency guaranteed;
// LDS 77824 B, VGPR <= 128).
// PROJ phase: block = 64 rows, 16 waves (wave>>2 = 16-row M-group, wave&3 ->
// 3 N-frags). Reg-staged double-buffered K-loop (r6/r16-proven), fragment-
// native LDS-bounce epilogue (r13-proven). Output layouts (per batch):
//   Q: tile(q>>5)*2048 + (d>>4)*512 + ((q&31)+32*((d>>3)&1))*8 + (d&7)
//   K: same with pi_inv(t&31) row permutation (rope applied, no prescale)
//   V: tile*2048 + (((d>>5)<<1)|((t&31)>>4))*512 + ((d&31)+32*((t>>3)&1))*8 + (t&7)
// BARRIER: device-scope atomic counter (zeroed by convert_w each call) +
// __threadfence release/acquire for cross-XCD L2 visibility.
// FLASH phase: r16 verbatim (16-way split-K, swapped QK^T, frag-native loads,
// register-rename P repack, running-base-m softmax, two-pass 16-way merge).
__global__ __launch_bounds__(1024) void fused_kernel(
    const float* __restrict__ x, const __bf16* __restrict__ wb,
    __bf16* __restrict__ qfb, __bf16* __restrict__ kfb, __bf16* __restrict__ vfb,
    float* __restrict__ out, u32* bar)
{
    __shared__ float smemf[19456];   // 77824 B union
    __bf16* sb = (__bf16*)smemf;
    __bf16 (*xs)[64][72]  = (__bf16(*)[64][72])sb;            // 9216 elems
    __bf16 (*wl)[192][72] = (__bf16(*)[192][72])(sb + 9216);  // 27648 elems
    __bf16* stage = sb;                                        // 12288 reuse
    float (*ods)[32][36] = (float(*)[32][36])smemf;            // flash: 18432 f
    float (*mls)[16][32] = (float(*)[16][32])(smemf + 18432);  // flash: 1024 f

    const int tid = threadIdx.x;
    const int wave = tid >> 6, lane = tid & 63;
    const int l15 = lane & 15, l4 = lane >> 4;
    const int l31 = lane & 31, h = lane >> 5;
    const int blk = blockIdx.x;

    // ======================= PROJ PHASE =======================
    {
        const int wm = wave >> 2;          // 0..3 : 16-row M-group
        const int wn = wave & 3;           // 0..3 : 3 N-frags each
        const size_t m0 = (size_t)blk * 64;
        const int xrow = tid >> 4, xc4 = (tid & 15) * 4;   // x: 16 thr/row
        const int wrow = tid >> 3, wcp = (tid & 7) * 8;    // W rows 0..127 (+128 for tid<512)

        f32x4 acc[3];
        #pragma unroll
        for (int nf = 0; nf < 3; nf++) acc[nf] = (f32x4){0.f, 0.f, 0.f, 0.f};

        const float* xsrc = x + (m0 + xrow) * 1024 + xc4;

        float4 rx;
        bf16x8 rw0, rw1;

        // prologue: tile 0 -> regs -> LDS buf 0
        rx = *(const float4*)(xsrc);
        rw0 = *(const bf16x8*)(wb + (size_t)wrow * 1024 + wcp);
        if (tid < 512)
            rw1 = *(const bf16x8*)(wb + (size_t)(128 + wrow) * 1024 + wcp);
        {
            bf16x4 hx = {(__bf16)rx.x, (__bf16)rx.y, (__bf16)rx.z, (__bf16)rx.w};
            *(bf16x4*)&xs[0][xrow][xc4] = hx;
            *(bf16x8*)&wl[0][wrow][wcp] = rw0;
            if (tid < 512) *(bf16x8*)&wl[0][128 + wrow][wcp] = rw1;
        }
        __syncthreads();

        for (int t = 0; t < 16; t++) {
            const int cur = t & 1;
            if (t < 15) {   // next tile's loads early (overlap with compute)
                const int k0 = (t + 1) * 64;
                rx = *(const float4*)(xsrc + k0);
                rw0 = *(const bf16x8*)(wb + (size_t)wrow * 1024 + k0 + wcp);
                if (tid < 512)
                    rw1 = *(const bf16x8*)(wb + (size_t)(128 + wrow) * 1024 + k0 + wcp);
            }
            // compute tile t from LDS[cur]
            bf16x8 af[2];
            #pragma unroll
            for (int c = 0; c < 2; c++)
                af[c] = *(const bf16x8*)&xs[cur][wm * 16 + l15][c * 32 + l4 * 8];
            #pragma unroll
            for (int nf = 0; nf < 3; nf++) {
                #pragma unroll
                for (int c = 0; c < 2; c++) {
                    bf16x8 bw = *(const bf16x8*)&wl[cur][(wn * 3 + nf) * 16 + l15][c * 32 + l4 * 8];
                    acc[nf] = mfma16(af[c], bw, acc[nf]);
                }
            }
            if (t < 15) {   // stage tile t+1 into the other buffer
                bf16x4 hx = {(__bf16)rx.x, (__bf16)rx.y, (__bf16)rx.z, (__bf16)rx.w};
                *(bf16x4*)&xs[cur ^ 1][xrow][xc4] = hx;
                *(bf16x8*)&wl[cur ^ 1][wrow][wcp] = rw0;
                if (tid < 512) *(bf16x8*)&wl[cur ^ 1][128 + wrow][wcp] = rw1;
            }
            __syncthreads();
        }

        // epilogue: rope + scatter into stage at fragment-native offsets
        const int tq0 = (int)(m0 & 4095);   // 64-aligned
        #pragma unroll
        for (int nf = 0; nf < 3; nf++) {
            int n = (wn * 3 + nf) * 16 + l15;
            #pragma unroll
            for (int r = 0; r < 4; r++) {
                int row64 = wm * 16 + l4 * 4 + r;
                int tile = row64 >> 5, rr = row64 & 31;
                int tb = tile * 6144;
                float val = acc[nf][r];
                float partner = __shfl_xor(val, 1);
                if (n < 128) {
                    int i = (n & 63) >> 1;
                    float ang = (float)(tq0 + row64)
                              * __builtin_exp2f((float)i * (-13.287712379549449f / 32.f));
                    float sn, cs;
                    __sincosf(ang, &sn, &cs);
                    float res = (n & 1) ? (partner * sn + val * cs)
                                        : (val * cs - partner * sn);
                    if (n < 64) {
                        res *= 0.180336884f;    // (1/8)*log2(e) folded into q
                        int d = n;
                        stage[tb + (d >> 4) * 512
                              + (rr + ((d >> 3) & 1) * 32) * 8 + (d & 7)] = (__bf16)res;
                    } else {
                        int d = n - 64;
                        int l31i = ((rr >> 2) & 1) * 16 + ((rr >> 4) & 1) * 8
                                 + ((rr >> 3) & 1) * 4 + (rr & 3);   // pi^-1
                        stage[tb + 2048 + (d >> 4) * 512
                              + (l31i + ((d >> 3) & 1) * 32) * 8 + (d & 7)] = (__bf16)res;
                    }
                } else {
                    int d = n - 128;
                    int cc = ((d >> 5) << 1) | (rr >> 4);
                    stage[tb + 4096 + cc * 512
                          + ((d & 31) + ((rr >> 3) & 1) * 32) * 8 + (rr & 7)]
                        = (__bf16)val;
                }
            }
        }
        __syncthreads();
        {
            const size_t bbase = (size_t)(m0 >> 12) * 262144;
            const size_t tbase = (size_t)((m0 & 4095) >> 5) * 2048;
            const int tile = tid >> 9;          // 0..1
            const int inner = (tid & 511) * 4;  // 0..2044
            const int tb = tile * 6144;
            const size_t go = bbase + tbase + (size_t)tile * 2048 + inner;
            bf16x4 q4 = *(const bf16x4*)&stage[tb + inner];
            bf16x4 k4 = *(const bf16x4*)&stage[tb + 2048 + inner];
            bf16x4 v4 = *(const bf16x4*)&stage[tb + 4096 + inner];
            *(bf16x4*)(qfb + go) = q4;
            *(bf16x4*)(kfb + go) = k4;
            *(bf16x4*)(vfb + go) = v4;
        }
    }

    // ======================= GLOBAL BARRIER =======================
    __threadfence();    // release: qkv stores visible device-wide
    __syncthreads();
    if (tid == 0) {
        __hip_atomic_fetch_add(bar, 1u, __ATOMIC_ACQ_REL, __HIP_MEMORY_SCOPE_AGENT);
        u32 v;
        do {
            __builtin_amdgcn_s_sleep(16);
            v = __hip_atomic_load(bar, __ATOMIC_ACQUIRE, __HIP_MEMORY_SCOPE_AGENT);
        } while (v < 256u);
    }
    __syncthreads();
    __threadfence();    // acquire: invalidate stale L1/L2 before reading qkv

    // ======================= FLASH PHASE =======================
    {
        const int xcd = blk & 7;
        const int b = xcd >> 1;
        const int p = ((blk >> 3) << 1) | (xcd & 1);   // 0..63 per batch

        const __bf16* qb_b = qfb + (size_t)b * 262144;
        const __bf16* kb_b = kfb + (size_t)b * 262144;
        const __bf16* vb_b = vfb + (size_t)b * 262144;

        #pragma unroll 1
        for (int half = 0; half < 2; half++) {
            const int jt = half ? p : 127 - p;
            const int q0 = jt * 32;
            const int qg = q0 + l31;

            const __bf16* qp = qb_b + (size_t)jt * 2048 + lane * 8;
            bf16x8 qf[4];
            #pragma unroll
            for (int dc = 0; dc < 4; dc++) qf[dc] = *(const bf16x8*)(qp + dc * 512);

            float m = 16.f, l = 0.f;
            f32x16 o0 = zero16(), o1 = zero16();
            const int nt = jt + 1;   // 32-row k-tiles

            #pragma unroll 1
            for (int kt = wave; kt < nt; kt += 16) {
                const int kc0 = kt << 5;
                const __bf16* kr = kb_b + (size_t)kt * 2048 + lane * 8;
                bf16x8 kf0 = *(const bf16x8*)(kr);
                bf16x8 kf1 = *(const bf16x8*)(kr + 512);
                bf16x8 kf2 = *(const bf16x8*)(kr + 1024);
                bf16x8 kf3 = *(const bf16x8*)(kr + 1536);
                const __bf16* vr = vb_b + (size_t)kt * 2048 + lane * 8;
                bf16x8 vf00 = *(const bf16x8*)(vr);
                bf16x8 vf01 = *(const bf16x8*)(vr + 512);
                bf16x8 vf10 = *(const bf16x8*)(vr + 1024);
                bf16x8 vf11 = *(const bf16x8*)(vr + 1536);
                f32x16 s = zero16();
                __builtin_amdgcn_s_setprio(1);
                s = mfma32(kf0, qf[0], s);
                s = mfma32(kf1, qf[1], s);
                s = mfma32(kf2, qf[2], s);
                s = mfma32(kf3, qf[3], s);
                __builtin_amdgcn_s_setprio(0);
                if (kt == jt) {
                    #pragma unroll
                    for (int r = 0; r < 16; r++) {
                        int pioff = ((r >> 2) & 1) * 16 + 8 * h + (r >> 3) * 4 + (r & 3);
                        if (kc0 + pioff > qg) s[r] = -1e30f;
                    }
                }
                float tm[8];
                #pragma unroll
                for (int i = 0; i < 8; i++) tm[i] = fmaxf(s[2 * i], s[2 * i + 1]);
                #pragma unroll
                for (int i = 0; i < 4; i++) tm[i] = fmaxf(tm[i], tm[i + 4]);
                float tmax = fmaxf(fmaxf(tm[0], tm[1]), fmaxf(tm[2], tm[3]));
                float ts[4] = {0.f, 0.f, 0.f, 0.f};
                #pragma unroll
                for (int r = 0; r < 16; r++) {
                    float e = __builtin_exp2f(s[r] - m);
                    s[r] = e;
                    ts[r & 3] += e;
                }
                float lsum = (ts[0] + ts[1]) + (ts[2] + ts[3]);
                float lsum_p = __shfl_xor(lsum, 32);
                float tmax_p = __shfl_xor(tmax, 32);
                union { u32 w[4]; bf16x8 v; } pf[2];
                #pragma unroll
                for (int cg = 0; cg < 2; cg++) {
                    pf[cg].w[0] = packbf(s[4 * cg + 0],  s[4 * cg + 1]);
                    pf[cg].w[1] = packbf(s[4 * cg + 2],  s[4 * cg + 3]);
                    pf[cg].w[2] = packbf(s[4 * cg + 8],  s[4 * cg + 9]);
                    pf[cg].w[3] = packbf(s[4 * cg + 10], s[4 * cg + 11]);
                }
                __builtin_amdgcn_s_setprio(1);
                o0 = mfma32(vf00, pf[0].v, o0);
                o0 = mfma32(vf01, pf[1].v, o0);
                o1 = mfma32(vf10, pf[0].v, o1);
                o1 = mfma32(vf11, pf[1].v, o1);
                __builtin_amdgcn_s_setprio(0);
                l += lsum + lsum_p;
                float tmx = fmaxf(tmax, tmax_p);
                if (!__all(tmx <= m + 8.f)) {
                    const float mnew = fmaxf(m, tmx);
                    const float alpha = __builtin_exp2f(m - mnew);
                    m = mnew;
                    l *= alpha;
                    #pragma unroll
                    for (int r = 0; r < 16; r++) { o0[r] *= alpha; o1[r] *= alpha; }
                }
            }

            // two-pass 16-way merge
            const int q = tid >> 5, dcm = tid & 31;
            #pragma unroll
            for (int c2 = 0; c2 < 4; c2++) {
                f32x4 w0 = {o0[4 * c2], o0[4 * c2 + 1], o0[4 * c2 + 2], o0[4 * c2 + 3]};
                *(f32x4*)&ods[wave][l31][8 * c2 + 4 * h] = w0;
            }
            if (h == 0) {
                mls[0][wave][l31] = (wave < nt) ? m : -1e30f;
                mls[1][wave][l31] = l;
            }
            __syncthreads();
            float M = -1e30f;
            #pragma unroll
            for (int s2 = 0; s2 < 16; s2++) M = fmaxf(M, mls[0][s2][q]);
            float w16[16], L = 0.f;
            #pragma unroll
            for (int s2 = 0; s2 < 16; s2++) {
                float ws = __builtin_exp2f(mls[0][s2][q] - M);
                w16[s2] = ws;
                L += ws * mls[1][s2][q];
            }
            const float invL = 1.f / L;
            float accA = 0.f;
            #pragma unroll
            for (int s2 = 0; s2 < 16; s2++) accA += w16[s2] * ods[s2][q][dcm];
            out[((size_t)b * T_LEN + q0 + q) * 64 + dcm] = accA * invL;
            __syncthreads();
            #pragma unroll
            for (int c2 = 0; c2 < 4; c2++) {
                f32x4 w1 = {o1[4 * c2], o1[4 * c2 + 1], o1[4 * c2 + 2], o1[4 * c2 + 3]};
                *(f32x4*)&ods[wave][l31][8 * c2 + 4 * h] = w1;
            }
            __syncthreads();
            float accB = 0.f;
            #pragma unroll
            for (int s2 = 0; s2 < 16; s2++) accB += w16[s2] * ods[s2][q][dcm];
            out[((size_t)b * T_LEN + q0 + q) * 64 + 32 + dcm] = accB * invL;
            __syncthreads();
        }
    }
}

extern "C" void kernel_launch(void* const* d_in, const int* in_sizes, int n_in,
                              void* d_out, int out_size, void* d_ws, size_t ws_size,
                              hipStream_t stream)
{
    const float* x  = (const float*)d_in[0];
    const float* Wq = (const float*)d_in[1];
    const float* Wk = (const float*)d_in[2];
    const float* Wv = (const float*)d_in[3];
    float* out = (float*)d_out;

    __bf16* qfb = (__bf16*)d_ws;         // 2 MB, fragment-native (rope+prescale)
    __bf16* kfb = qfb + 1048576;         // 2 MB, fragment-native (rope, pi-permuted)
    __bf16* vfb = kfb + 1048576;         // 2 MB, fragment-native (PV operand order)
    __bf16* wb  = vfb + 1048576;         // 384 KB, row-major W
    u32*    bar = (u32*)(wb + 196608);   // global-barrier counter

    convert_w_kernel<<<192, 256, 0, stream>>>(Wq, Wk, Wv, wb, bar);
    fused_kernel<<<256, 1024, 0, stream>>>(x, wb, qfb, kfb, vfb, out, bar);
}

// Round 18
// 54.163 us; speedup vs baseline: 3.7772x; 3.7772x over previous
//
#include <hip/hip_runtime.h>

typedef __bf16 bf16x8 __attribute__((ext_vector_type(8)));
typedef __bf16 bf16x4 __attribute__((ext_vector_type(4)));
typedef float f32x4 __attribute__((ext_vector_type(4)));
typedef float f32x16 __attribute__((ext_vector_type(16)));
typedef unsigned int u32;

#define T_LEN 4096

__device__ __forceinline__ f32x4 mfma16(bf16x8 a, bf16x8 b, f32x4 c) {
    return __builtin_amdgcn_mfma_f32_16x16x32_bf16(a, b, c, 0, 0, 0);
}
__device__ __forceinline__ f32x16 mfma32(bf16x8 a, bf16x8 b, f32x16 c) {
    return __builtin_amdgcn_mfma_f32_32x32x16_bf16(a, b, c, 0, 0, 0);
}
__device__ __forceinline__ u32 packbf(float lo, float hi) {
    union { __bf16 e[2]; u32 w; } u;
    u.e[0] = (__bf16)lo; u.e[1] = (__bf16)hi;
    return u.w;
}
__device__ __forceinline__ f32x16 zero16() {
    f32x16 z;
    #pragma unroll
    for (int i = 0; i < 16; i++) z[i] = 0.f;
    return z;
}
// async global->LDS, 16B per lane; LDS dest is wave-uniform base + lane*16
__device__ __forceinline__ void gload_lds16(const __bf16* g, __bf16* l) {
    __builtin_amdgcn_global_load_lds(
        (const __attribute__((address_space(1))) u32*)g,
        (__attribute__((address_space(3))) u32*)l, 16, 0, 0);
}

// ---- W fp32 -> bf16, K-tiled + XOR-swizzled chunk order for global_load_lds ----
// Tile ks (0..15) = [192 rows][64 cols] bf16, 8 chunks(16B)/row.
// Element (n, kc=g*8+j) stored at chunk n*8 + (g ^ (n&7)), elem j.
// (So linear LDS writes + XOR'd ds_read addr give conflict-free B-frag reads.)
__global__ __launch_bounds__(256) void convert_w_kernel(
    const float* __restrict__ Wq, const float* __restrict__ Wk,
    const float* __restrict__ Wv, __bf16* __restrict__ wf)
{
    int t = blockIdx.x * 256 + threadIdx.x;   // 24576 threads: (ks, n, g)
    int ks = t / 1536;
    int rem = t - ks * 1536;
    int n = rem >> 3, g = rem & 7;
    const float* src = (n < 64 ? Wq : (n < 128 ? Wk : Wv))
                     + (size_t)(n & 63) * 1024 + ks * 64 + g * 8;
    float4 f0 = *(const float4*)src;
    float4 f1 = *(const float4*)(src + 4);
    bf16x8 h = {(__bf16)f0.x, (__bf16)f0.y, (__bf16)f0.z, (__bf16)f0.w,
                (__bf16)f1.x, (__bf16)f1.y, (__bf16)f1.z, (__bf16)f1.w};
    int chunk = n * 8 + (g ^ (n & 7));
    *(bf16x8*)(wf + (size_t)ks * 12288 + chunk * 8) = h;
}

// ------ QKV projection (M=16384,N=192,K=1024) + fused RoPE + q-prescale ------
// 256 blocks x 64 rows, 8 waves (2M x 4N). x: reg-staged dbuf (r16). W: staged
// via global_load_lds (3 x 16B per thread per K-step) into linear LDS from the
// pre-swizzled wf; ds_reads use the XOR'd chunk address (conflict-free).
// Epilogue (r13-proven): rope -> LDS scatter at fragment-native intra-tile
// offsets -> coalesced bf16x4 copy-out.
__global__ __launch_bounds__(512, 2) void proj_kernel(
    const float* __restrict__ x, const __bf16* __restrict__ wf,
    __bf16* __restrict__ qfb, __bf16* __restrict__ kfb, __bf16* __restrict__ vfb)
{
    __shared__ __bf16 smem[33792];   // xs[2][64][72] (9216) | wl[2][12288] (24576)
    __bf16 (*xs)[64][72] = (__bf16(*)[64][72])smem;
    __bf16* wl = smem + 9216;
    __bf16* stage = smem;            // [2][3][2048] = 12288, reused after loop

    const int tid  = threadIdx.x;
    const int wave = tid >> 6, lane = tid & 63;
    const int l15 = lane & 15, l4 = lane >> 4;
    const int wm = wave >> 2, wn = wave & 3;     // 2 M-halves x 4 N-groups
    const size_t m0 = (size_t)blockIdx.x * 64;
    const int srow = tid >> 3, scp = (tid & 7) * 8;

    f32x4 acc[2][3];
    #pragma unroll
    for (int a = 0; a < 2; a++)
        #pragma unroll
        for (int bn = 0; bn < 3; bn++) acc[a][bn] = (f32x4){0.f, 0.f, 0.f, 0.f};

    const float* xsrc = x + (m0 + srow) * 1024 + scp;

    float4 rx0, rx1;

    // prologue: x tile 0 -> regs -> LDS buf 0; W tile 0 -> LDS buf 0 (async)
    rx0 = *(const float4*)(xsrc);
    rx1 = *(const float4*)(xsrc + 4);
    {
        bf16x8 h = {(__bf16)rx0.x, (__bf16)rx0.y, (__bf16)rx0.z, (__bf16)rx0.w,
                    (__bf16)rx1.x, (__bf16)rx1.y, (__bf16)rx1.z, (__bf16)rx1.w};
        *(bf16x8*)&xs[0][srow][scp] = h;
        __bf16* wdst = wl + wave * 512;
        #pragma unroll
        for (int i = 0; i < 3; i++)
            gload_lds16(wf + (size_t)i * 4096 + (size_t)tid * 8, wdst + i * 4096);
    }
    __syncthreads();

    for (int t = 0; t < 16; t++) {
        const int cur = t & 1;
        if (t < 15) {   // issue next tile's loads early (overlap with compute)
            const int k0 = (t + 1) * 64;
            rx0 = *(const float4*)(xsrc + k0);
            rx1 = *(const float4*)(xsrc + k0 + 4);
            const __bf16* wsrc = wf + (size_t)(t + 1) * 12288;
            __bf16* wdst = wl + (cur ^ 1) * 12288 + wave * 512;
            #pragma unroll
            for (int i = 0; i < 3; i++)
                gload_lds16(wsrc + (size_t)i * 4096 + (size_t)tid * 8, wdst + i * 4096);
        }
        // compute tile t from LDS[cur]
        const __bf16* wcur = wl + cur * 12288;
        bf16x8 af[2][2];
        #pragma unroll
        for (int mf = 0; mf < 2; mf++)
            #pragma unroll
            for (int c = 0; c < 2; c++)
                af[mf][c] = *(const bf16x8*)&xs[cur][wm * 32 + mf * 16 + l15][c * 32 + l4 * 8];
        #pragma unroll
        for (int nf = 0; nf < 3; nf++) {
            const int n = wn * 48 + nf * 16 + l15;
            const int sw = n & 7;
            #pragma unroll
            for (int c = 0; c < 2; c++) {
                bf16x8 bw = *(const bf16x8*)(wcur + (size_t)(n * 8 + ((c * 4 + l4) ^ sw)) * 8);
                #pragma unroll
                for (int mf = 0; mf < 2; mf++)
                    acc[mf][nf] = mfma16(af[mf][c], bw, acc[mf][nf]);
            }
        }
        if (t < 15) {   // stage x tile t+1 into the other buffer
            bf16x8 h = {(__bf16)rx0.x, (__bf16)rx0.y, (__bf16)rx0.z, (__bf16)rx0.w,
                        (__bf16)rx1.x, (__bf16)rx1.y, (__bf16)rx1.z, (__bf16)rx1.w};
            *(bf16x8*)&xs[cur ^ 1][srow][scp] = h;
        }
        __syncthreads();
    }
    // loop-final barrier passed: all LDS reads done; smem reusable as stage.

    // epilogue: C layout col = l15 (n), row64 = wm*32 + mf*16 + l4*4 + r;
    // rope fused for q,k; q pre-scaled by (1/8)*log2(e); scatter into LDS
    // stage[tile][out][2048], then coalesced copy-out.
    const int tq0 = (int)(m0 & 4095);   // 64-aligned
    #pragma unroll
    for (int nf = 0; nf < 3; nf++) {
        int n = wn * 48 + nf * 16 + l15;
        #pragma unroll
        for (int mf = 0; mf < 2; mf++) {
            #pragma unroll
            for (int r = 0; r < 4; r++) {
                int row64 = wm * 32 + mf * 16 + l4 * 4 + r;
                int tile = row64 >> 5, rr = row64 & 31;
                int tb = tile * 6144;
                float val = acc[mf][nf][r];
                float partner = __shfl_xor(val, 1);
                if (n < 128) {
                    int i = (n & 63) >> 1;
                    float ang = (float)(tq0 + row64)
                              * __builtin_exp2f((float)i * (-13.287712379549449f / 32.f));
                    float sn, cs;
                    __sincosf(ang, &sn, &cs);
                    float res = (n & 1) ? (partner * sn + val * cs)
                                        : (val * cs - partner * sn);
                    if (n < 64) {
                        res *= 0.180336884f;    // (1/8)*log2(e) folded into q
                        int d = n;
                        stage[tb + (d >> 4) * 512
                              + (rr + ((d >> 3) & 1) * 32) * 8 + (d & 7)] = (__bf16)res;
                    } else {
                        int d = n - 64;
                        int l31i = ((rr >> 2) & 1) * 16 + ((rr >> 4) & 1) * 8
                                 + ((rr >> 3) & 1) * 4 + (rr & 3);   // pi^-1
                        stage[tb + 2048 + (d >> 4) * 512
                              + (l31i + ((d >> 3) & 1) * 32) * 8 + (d & 7)] = (__bf16)res;
                    }
                } else {
                    int d = n - 128;
                    int cc = ((d >> 5) << 1) | (rr >> 4);
                    stage[tb + 4096 + cc * 512
                          + ((d & 31) + ((rr >> 3) & 1) * 32) * 8 + (rr & 7)]
                        = (__bf16)val;
                }
            }
        }
    }
    __syncthreads();
    {
        const size_t bbase = (size_t)(m0 >> 12) * 262144;
        const size_t tbase = (size_t)((m0 & 4095) >> 5) * 2048;   // first 32-row tile
        #pragma unroll
        for (int tile = 0; tile < 2; tile++) {
            const int tb = tile * 6144;
            const size_t go = bbase + tbase + (size_t)tile * 2048 + tid * 4;
            bf16x4 q4 = *(const bf16x4*)&stage[tb + tid * 4];
            bf16x4 k4 = *(const bf16x4*)&stage[tb + 2048 + tid * 4];
            bf16x4 v4 = *(const bf16x4*)&stage[tb + 4096 + tid * 4];
            *(bf16x4*)(qfb + go) = q4;
            *(bf16x4*)(kfb + go) = k4;
            *(bf16x4*)(vfb + go) = v4;
        }
    }
}

// ---------------- causal flash attention, 1024-thread blocks ----------------
// 256 blocks = 1/CU. XCD-affine: b=(blk&7)>>1. Serial heavy (127-p) + light (p)
// halves -> balanced per CU. 16 waves = 16-way split-K over 32-row k-tiles.
// Swapped QK^T (lane -> one q col); fragment-native layouts make every load
// lane-consecutive (coalesced). pi permutation baked into kfb at store time;
// P->B-frag repack is a pure register rename. exp2 uses running base m.
__global__ __launch_bounds__(1024) void flash_kernel(
    const __bf16* __restrict__ qfb, const __bf16* __restrict__ kfb,
    const __bf16* __restrict__ vfb, float* __restrict__ out)
{
    __shared__ float ods[16][32][36];   // two-pass merge buffer (o0 then o1)
    __shared__ float mls[2][16][32];

    const int tid = threadIdx.x;
    const int wave = tid >> 6, lane = tid & 63;
    const int l31 = lane & 31, h = lane >> 5;
    const int xcd = blockIdx.x & 7;
    const int b = xcd >> 1;
    const int p = ((blockIdx.x >> 3) << 1) | (xcd & 1);   // 0..63 per batch

    const __bf16* qb_b = qfb + (size_t)b * 262144;
    const __bf16* kb_b = kfb + (size_t)b * 262144;
    const __bf16* vb_b = vfb + (size_t)b * 262144;

    #pragma unroll 1
    for (int half = 0; half < 2; half++) {
        const int jt = half ? p : 127 - p;
        const int q0 = jt * 32;
        const int qg = q0 + l31;

        // Q B-frags: coalesced tile load
        const __bf16* qp = qb_b + (size_t)jt * 2048 + lane * 8;
        bf16x8 qf[4];
        #pragma unroll
        for (int dc = 0; dc < 4; dc++) qf[dc] = *(const bf16x8*)(qp + dc * 512);

        float m = 16.f, l = 0.f;
        f32x16 o0 = zero16(), o1 = zero16();
        const int nt = jt + 1;   // 32-row k-tiles

        #pragma unroll 1
        for (int kt = wave; kt < nt; kt += 16) {
            const int kc0 = kt << 5;
            // K + V frags: coalesced tile loads
            const __bf16* kr = kb_b + (size_t)kt * 2048 + lane * 8;
            bf16x8 kf0 = *(const bf16x8*)(kr);
            bf16x8 kf1 = *(const bf16x8*)(kr + 512);
            bf16x8 kf2 = *(const bf16x8*)(kr + 1024);
            bf16x8 kf3 = *(const bf16x8*)(kr + 1536);
            const __bf16* vr = vb_b + (size_t)kt * 2048 + lane * 8;
            bf16x8 vf00 = *(const bf16x8*)(vr);          // d 0..31,  cg 0
            bf16x8 vf01 = *(const bf16x8*)(vr + 512);    // d 0..31,  cg 1
            bf16x8 vf10 = *(const bf16x8*)(vr + 1024);   // d 32..63, cg 0
            bf16x8 vf11 = *(const bf16x8*)(vr + 1536);   // d 32..63, cg 1
            f32x16 s = zero16();
            __builtin_amdgcn_s_setprio(1);
            s = mfma32(kf0, qf[0], s);
            s = mfma32(kf1, qf[1], s);
            s = mfma32(kf2, qf[2], s);
            s = mfma32(kf3, qf[3], s);
            __builtin_amdgcn_s_setprio(0);
            // causal mask: only the diagonal tile straddles
            if (kt == jt) {
                #pragma unroll
                for (int r = 0; r < 16; r++) {
                    int pioff = ((r >> 2) & 1) * 16 + 8 * h + (r >> 3) * 4 + (r & 3);
                    if (kc0 + pioff > qg) s[r] = -1e30f;
                }
            }
            // local max tree (defer check only; does NOT gate the exp)
            float tm[8];
            #pragma unroll
            for (int i = 0; i < 8; i++) tm[i] = fmaxf(s[2 * i], s[2 * i + 1]);
            #pragma unroll
            for (int i = 0; i < 4; i++) tm[i] = fmaxf(tm[i], tm[i + 4]);
            float tmax = fmaxf(fmaxf(tm[0], tm[1]), fmaxf(tm[2], tm[3]));
            // exp2 against running base m — no reduction wait on critical path
            float ts[4] = {0.f, 0.f, 0.f, 0.f};
            #pragma unroll
            for (int r = 0; r < 16; r++) {
                float e = __builtin_exp2f(s[r] - m);
                s[r] = e;
                ts[r & 3] += e;
            }
            float lsum = (ts[0] + ts[1]) + (ts[2] + ts[3]);
            // cross-half exchanges issued now, consumed after PV
            float lsum_p = __shfl_xor(lsum, 32);
            float tmax_p = __shfl_xor(tmax, 32);
            // P -> B-frags: pure register rename under pi (no shuffles)
            union { u32 w[4]; bf16x8 v; } pf[2];
            #pragma unroll
            for (int cg = 0; cg < 2; cg++) {
                pf[cg].w[0] = packbf(s[4 * cg + 0],  s[4 * cg + 1]);
                pf[cg].w[1] = packbf(s[4 * cg + 2],  s[4 * cg + 3]);
                pf[cg].w[2] = packbf(s[4 * cg + 8],  s[4 * cg + 9]);
                pf[cg].w[3] = packbf(s[4 * cg + 10], s[4 * cg + 11]);
            }
            // PV: O^T += V^T P^T
            __builtin_amdgcn_s_setprio(1);
            o0 = mfma32(vf00, pf[0].v, o0);
            o0 = mfma32(vf01, pf[1].v, o0);
            o1 = mfma32(vf10, pf[0].v, o1);
            o1 = mfma32(vf11, pf[1].v, o1);
            __builtin_amdgcn_s_setprio(0);
            // fold reductions; rescale AFTER accumulation (tile used base m)
            l += lsum + lsum_p;
            float tmx = fmaxf(tmax, tmax_p);
            if (!__all(tmx <= m + 8.f)) {
                const float mnew = fmaxf(m, tmx);
                const float alpha = __builtin_exp2f(m - mnew);
                m = mnew;
                l *= alpha;
                #pragma unroll
                for (int r = 0; r < 16; r++) { o0[r] *= alpha; o1[r] *= alpha; }
            }
        }

        // ---- two-pass 16-way merge; O^T C-layout col q=l31, row d=(r&3)+8*(r>>2)+4h
        const int q = tid >> 5, dcm = tid & 31;
        // pass A: d = 0..31 (o0)
        #pragma unroll
        for (int c2 = 0; c2 < 4; c2++) {
            f32x4 w0 = {o0[4 * c2], o0[4 * c2 + 1], o0[4 * c2 + 2], o0[4 * c2 + 3]};
            *(f32x4*)&ods[wave][l31][8 * c2 + 4 * h] = w0;
        }
        if (h == 0) {
            mls[0][wave][l31] = (wave < nt) ? m : -1e30f;   // empty splits: weight 0
            mls[1][wave][l31] = l;
        }
        __syncthreads();
        float M = -1e30f;
        #pragma unroll
        for (int s2 = 0; s2 < 16; s2++) M = fmaxf(M, mls[0][s2][q]);
        float w16[16], L = 0.f;
        #pragma unroll
        for (int s2 = 0; s2 < 16; s2++) {
            float ws = __builtin_exp2f(mls[0][s2][q] - M);
            w16[s2] = ws;
            L += ws * mls[1][s2][q];
        }
        const float invL = 1.f / L;
        float accA = 0.f;
        #pragma unroll
        for (int s2 = 0; s2 < 16; s2++) accA += w16[s2] * ods[s2][q][dcm];
        out[((size_t)b * T_LEN + q0 + q) * 64 + dcm] = accA * invL;
        __syncthreads();
        // pass B: d = 32..63 (o1)
        #pragma unroll
        for (int c2 = 0; c2 < 4; c2++) {
            f32x4 w1 = {o1[4 * c2], o1[4 * c2 + 1], o1[4 * c2 + 2], o1[4 * c2 + 3]};
            *(f32x4*)&ods[wave][l31][8 * c2 + 4 * h] = w1;
        }
        __syncthreads();
        float accB = 0.f;
        #pragma unroll
        for (int s2 = 0; s2 < 16; s2++) accB += w16[s2] * ods[s2][q][dcm];
        out[((size_t)b * T_LEN + q0 + q) * 64 + 32 + dcm] = accB * invL;
        __syncthreads();
    }
}

extern "C" void kernel_launch(void* const* d_in, const int* in_sizes, int n_in,
                              void* d_out, int out_size, void* d_ws, size_t ws_size,
                              hipStream_t stream)
{
    const float* x  = (const float*)d_in[0];
    const float* Wq = (const float*)d_in[1];
    const float* Wk = (const float*)d_in[2];
    const float* Wv = (const float*)d_in[3];
    float* out = (float*)d_out;

    __bf16* qfb = (__bf16*)d_ws;         // 2 MB, fragment-native (rope+prescale)
    __bf16* kfb = qfb + 1048576;         // 2 MB, fragment-native (rope, pi-permuted)
    __bf16* vfb = kfb + 1048576;         // 2 MB, fragment-native (PV operand order)
    __bf16* wf  = vfb + 1048576;         // 384 KB, K-tiled swizzled W

    convert_w_kernel<<<96, 256, 0, stream>>>(Wq, Wk, Wv, wf);
    proj_kernel<<<256, 512, 0, stream>>>(x, wf, qfb, kfb, vfb);
    flash_kernel<<<256, 1024, 0, stream>>>(qfb, kfb, vfb, out);
}